// Round 3
// baseline (560.204 us; speedup 1.0000x reference)
//
#include <hip/hip_runtime.h>

typedef __attribute__((ext_vector_type(8))) short short8;
typedef __attribute__((ext_vector_type(4))) short short4_;
typedef __attribute__((ext_vector_type(4))) float f32x4;
typedef __attribute__((ext_vector_type(4))) unsigned int u32x4;

#define AS1 __attribute__((address_space(1)))
#define AS3 __attribute__((address_space(3)))
#define GLD16(g, l) __builtin_amdgcn_global_load_lds((const AS1 void*)(g), (AS3 void*)(l), 16, 0, 0)

#define C2 0.12751743f  /* log2(e)/sqrt(128) */

__device__ __forceinline__ unsigned short f2bf(float f) {
  unsigned int u = __float_as_uint(f);
  u += 0x7fffu + ((u >> 16) & 1u);   // RNE
  return (unsigned short)(u >> 16);
}
__device__ __forceinline__ unsigned int cvtpk(float a, float b) {
  unsigned int r;
  asm("v_cvt_pk_bf16_f32 %0, %1, %2" : "=v"(r) : "v"(a), "v"(b));
  return r;
}
__device__ __forceinline__ float max3f(float a, float b, float c) {
  float r;
  asm("v_max3_f32 %0, %1, %2, %3" : "=v"(r) : "v"(a), "v"(b), "v"(c));
  return r;
}

// ---------------- weight transpose: [K][N] f32 -> [N][K] bf16 ----------------
__global__ __launch_bounds__(256) void k_transpose_w(
    const float* __restrict__ wq, const float* __restrict__ wk,
    const float* __restrict__ wv, const float* __restrict__ wo,
    unsigned short* __restrict__ wqkvT, unsigned short* __restrict__ woT)
{
  __shared__ float tile[64][65];
  const int z = blockIdx.z;
  const float* src = (z == 0) ? wq : (z == 1) ? wk : (z == 2) ? wv : wo;
  unsigned short* dst = (z == 3) ? woT : (wqkvT + (size_t)z * 2048 * 2048);
  const int k0 = blockIdx.y * 64, n0 = blockIdx.x * 64;
  const int tid = threadIdx.x;
#pragma unroll
  for (int p = 0; p < 4; ++p) {
    const int r = p * 16 + (tid >> 4);
    const int c = (tid & 15) * 4;
    f32x4 v = *(const f32x4*)(src + (size_t)(k0 + r) * 2048 + n0 + c);
    tile[r][c + 0] = v[0]; tile[r][c + 1] = v[1];
    tile[r][c + 2] = v[2]; tile[r][c + 3] = v[3];
  }
  __syncthreads();
#pragma unroll
  for (int p = 0; p < 2; ++p) {
    const int task = tid + p * 256;
    const int n = task >> 3;
    const int kc = (task & 7) * 8;
    short8 ov;
#pragma unroll
    for (int j = 0; j < 8; ++j) ov[j] = (short)f2bf(tile[kc + j][n]);
    *(short8*)(dst + (size_t)(n0 + n) * 2048 + k0 + kc) = ov;
  }
}

// ------------- convert x / cache_k / cache_v f32 -> bf16 -------------
__global__ __launch_bounds__(256) void k_convert(
    const float* __restrict__ x, const float* __restrict__ ck, const float* __restrict__ cv,
    unsigned short* __restrict__ xbf, unsigned short* __restrict__ kfull,
    unsigned short* __restrict__ vfull)
{
  const int z = blockIdx.y;
  const size_t idx = ((size_t)blockIdx.x * 256 + threadIdx.x) * 8;
  const float* src = (z == 0) ? x : (z == 1) ? ck : cv;
  f32x4 a = *(const f32x4*)(src + idx);
  f32x4 b = *(const f32x4*)(src + idx + 4);
  short8 ov;
#pragma unroll
  for (int j = 0; j < 4; ++j) { ov[j] = (short)f2bf(a[j]); ov[j + 4] = (short)f2bf(b[j]); }
  unsigned short* dp; size_t di;
  if (z == 0) { dp = xbf; di = idx; }
  else {
    const size_t r = idx >> 11, cl = idx & 2047;
    const size_t orow = r + (r & ~(size_t)2047);   // cache rows -> [b*4096 + p]
    di = orow * 2048 + cl;
    dp = (z == 1) ? kfull : vfull;
  }
  *(short8*)(dp + di) = ov;
}

// ======== pipelined 256x256 QKV GEMM (T2+T3+T4+T5): C = A * BT^T + bias ========
// 8 waves (2Mx4N), BK=32, ring-4 LDS buffers (128KB dynamic), stage tile t+2 while
// computing tile t, per-tile counted vmcnt(4) BEFORE the barrier (never drains to 0).
__global__ __launch_bounds__(512, 2) void k_gemm8(
    const unsigned short* __restrict__ A, const unsigned short* __restrict__ BT,
    unsigned short* __restrict__ Oq, unsigned short* __restrict__ Ok,
    unsigned short* __restrict__ Ov,
    const float* __restrict__ b0, const float* __restrict__ b1,
    const float* __restrict__ b2)
{
  extern __shared__ char lds[];            // 131072: A ring 4x16KB, B ring 4x16KB
  char* ABase = lds;
  char* BBase = lds + 65536;
  const int tid = threadIdx.x;
  const int l = tid & 63, w = tid >> 6;
  const int l15 = l & 15, g = l >> 4;
  const int wr = w >> 2, wc = w & 3;       // wave tile: rows wr*128, cols wc*64
  const int bid = blockIdx.x;
  const int sw = (bid & 7) * 48 + (bid >> 3);   // XCD swizzle (384 = 8*48)
  const int bm = sw / 24, bn = sw % 24;

  const unsigned short* Ab = A + (size_t)bm * 256 * 2048;
  const unsigned short* Bb = BT + (size_t)bn * 256 * 2048;
  const int sr = l >> 2;    // staging: row within 16-row chunk
  const int su = l & 3;     // 16B unit within 64B row

  f32x4 acc[8][4];
#pragma unroll
  for (int i = 0; i < 8; ++i)
#pragma unroll
    for (int j = 0; j < 4; ++j)
#pragma unroll
      for (int e = 0; e < 4; ++e) acc[i][j][e] = 0.f;

  // stage one matrix-tile (256x32 = 16KB): 2 GLD16 per wave; LDS linear,
  // source column rotated by (row>>1)&3 so reads at u'=(ku+(row>>1))&3 are conflict-free
  auto STAGE = [&](const unsigned short* src, char* base, int slot, int tt) {
    char* dst = base + slot * 16384 + w * 2048;
#pragma unroll
    for (int i = 0; i < 2; ++i) {
      const int row = w * 32 + i * 16 + sr;
      const int gu = (su - (row >> 1)) & 3;
      GLD16(src + (size_t)row * 2048 + tt * 32 + gu * 8, dst + i * 1024);
    }
  };

  // prologue: tiles 0,1
  STAGE(Ab, ABase, 0, 0); STAGE(Bb, BBase, 0, 0);
  STAGE(Ab, ABase, 1, 1); STAGE(Bb, BBase, 1, 1);
  asm volatile("s_waitcnt vmcnt(4)" ::: "memory");
  __builtin_amdgcn_sched_barrier(0);
  __builtin_amdgcn_s_barrier();

  for (int t = 0; t < 64; ++t) {
    const char* Ac = ABase + (t & 3) * 16384;
    const char* Bc = BBase + (t & 3) * 16384;
    const int t2 = (t + 2 < 64) ? t + 2 : 0;
    const int s2 = (t + 2) & 3;
    short8 av[4], bv[4];
    // --- phase 1: A mf0-3 + B nf0-3 reads, stage A(t+2) ---
#pragma unroll
    for (int mf = 0; mf < 4; ++mf) {
      const int ar = wr * 128 + mf * 16 + l15;
      av[mf] = *(const short8*)(Ac + ar * 64 + (((g + (ar >> 1)) & 3) * 16));
    }
#pragma unroll
    for (int nf = 0; nf < 4; ++nf) {
      const int br = wc * 64 + nf * 16 + l15;
      bv[nf] = *(const short8*)(Bc + br * 64 + (((g + (br >> 1)) & 3) * 16));
    }
    STAGE(Ab, ABase, s2, t2);
    __builtin_amdgcn_s_barrier();
    asm volatile("s_waitcnt lgkmcnt(0)" ::: "memory");
    __builtin_amdgcn_sched_barrier(0);
    __builtin_amdgcn_s_setprio(1);
#pragma unroll
    for (int mf = 0; mf < 4; ++mf)
#pragma unroll
      for (int nf = 0; nf < 4; ++nf)
        acc[mf][nf] = __builtin_amdgcn_mfma_f32_16x16x32_bf16(av[mf], bv[nf], acc[mf][nf], 0, 0, 0);
    __builtin_amdgcn_s_setprio(0);
    __builtin_amdgcn_s_barrier();
    // --- phase 2: A mf4-7 reads (reuse B), stage B(t+2) ---
#pragma unroll
    for (int mf = 0; mf < 4; ++mf) {
      const int ar = wr * 128 + (mf + 4) * 16 + l15;
      av[mf] = *(const short8*)(Ac + ar * 64 + (((g + (ar >> 1)) & 3) * 16));
    }
    STAGE(Bb, BBase, s2, t2);
    __builtin_amdgcn_s_barrier();
    asm volatile("s_waitcnt lgkmcnt(0)" ::: "memory");
    __builtin_amdgcn_sched_barrier(0);
    __builtin_amdgcn_s_setprio(1);
#pragma unroll
    for (int mf = 0; mf < 4; ++mf)
#pragma unroll
      for (int nf = 0; nf < 4; ++nf)
        acc[mf + 4][nf] = __builtin_amdgcn_mfma_f32_16x16x32_bf16(av[mf], bv[nf], acc[mf + 4][nf], 0, 0, 0);
    __builtin_amdgcn_s_setprio(0);
    asm volatile("s_waitcnt vmcnt(4)" ::: "memory");   // t+1 landed; t+2 still in flight
    __builtin_amdgcn_sched_barrier(0);
    __builtin_amdgcn_s_barrier();
  }

  // --- epilogue: bias + q/k/v routing ---
  const int nglob0 = bn * 256;
  const int nsec = nglob0 >> 11;            // 0=q,1=k,2=v (uniform per block)
  unsigned short* dst = (nsec == 0) ? Oq : (nsec == 1) ? Ok : Ov;
  const float* bias = (nsec == 0) ? b0 : (nsec == 1) ? b1 : b2;
#pragma unroll
  for (int nf = 0; nf < 4; ++nf) {
    const int cc = (nglob0 & 2047) + wc * 64 + nf * 16 + l15;
    const float bb = bias[cc];
#pragma unroll
    for (int mf = 0; mf < 8; ++mf) {
#pragma unroll
      for (int ii = 0; ii < 4; ++ii) {
        const int rr = bm * 256 + wr * 128 + mf * 16 + g * 4 + ii;
        const size_t orow = (nsec == 0) ? (size_t)rr : (size_t)(rr + (rr & ~2047) + 2048);
        dst[orow * 2048 + cc] = f2bf(acc[mf][nf][ii] + bb);
      }
    }
  }
}

// ---------------- GEMM (m97-style 128^2): C[M,N] = A[M,K]*BT[N,K]^T + bias, f32 out ----------------
__global__ __launch_bounds__(256, 2) void k_gemmo(
    const unsigned short* __restrict__ A, const unsigned short* __restrict__ BT,
    float* __restrict__ Of, const float* __restrict__ b0, int K)
{
  __shared__ unsigned short Ah[128 * 32];
  __shared__ unsigned short Bh[128 * 32];
  const int tid = threadIdx.x;
  const int l = tid & 63, w = tid >> 6;
  const int l15 = l & 15, g = l >> 4;
  const int wr = (w >> 1) * 64, wc = (w & 1) * 64;
  const int bm = blockIdx.y, bn = blockIdx.x;
  const unsigned short* Ab = A + (size_t)bm * 128 * K;
  const unsigned short* Bb = BT + (size_t)bn * 128 * K;
  const int srow = l >> 2;
  const int scol = (l & 3) * 8;
  f32x4 acc[4][4];
#pragma unroll
  for (int i = 0; i < 4; ++i)
#pragma unroll
    for (int j = 0; j < 4; ++j)
#pragma unroll
      for (int e = 0; e < 4; ++e) acc[i][j][e] = 0.f;

  for (int kt = 0; kt < K; kt += 32) {
#pragma unroll
    for (int cc = 0; cc < 2; ++cc) {
      const int c = w + cc * 4;
      GLD16(Ab + (size_t)(c * 16 + srow) * K + kt + scol, &Ah[c * 512]);
      GLD16(Bb + (size_t)(c * 16 + srow) * K + kt + scol, &Bh[c * 512]);
    }
    __syncthreads();
    short8 af[4], bf[4];
#pragma unroll
    for (int i = 0; i < 4; ++i) {
      af[i] = *(const short8*)&Ah[(wr + i * 16 + l15) * 32 + g * 8];
      bf[i] = *(const short8*)&Bh[(wc + i * 16 + l15) * 32 + g * 8];
    }
#pragma unroll
    for (int i = 0; i < 4; ++i)
#pragma unroll
      for (int j = 0; j < 4; ++j)
        acc[i][j] = __builtin_amdgcn_mfma_f32_16x16x32_bf16(af[i], bf[j], acc[i][j], 0, 0, 0);
    __syncthreads();
  }
#pragma unroll
  for (int j = 0; j < 4; ++j) {
    const int cc = bn * 128 + wc + j * 16 + l15;
    const float bb = b0[cc];
#pragma unroll
    for (int i = 0; i < 4; ++i) {
#pragma unroll
      for (int ii = 0; ii < 4; ++ii) {
        const int rr = bm * 128 + wr + g * 4 + i * 16 + ii;
        Of[(size_t)rr * 2048 + cc] = acc[i][j][ii] + bb;
      }
    }
  }
}

// ---------------- flash attention (v3) ----------------
// QBLK=128 (4 waves x 32 q-rows, 2 groups), KBLK=64, double-buffered LDS.
// cvt_pk P-packing, max3 reductions, V LDS-write deferred past softmax (T14).
__global__ __launch_bounds__(256, 2) void k_flash(
    const unsigned short* __restrict__ qbuf, const unsigned short* __restrict__ kfull,
    const unsigned short* __restrict__ vfull, unsigned short* __restrict__ attnout)
{
  __shared__ char smem[65536];
  const int tid = threadIdx.x;
  const int l = tid & 63, w = tid >> 6;
  const int l15 = l & 15, g = l >> 4;
  const int bid = blockIdx.x;
  const int sw = (bid & 7) * 64 + (bid >> 3);   // XCD swizzle: whole (b,h) groups per XCD
  const int qt = sw & 15, bh = sw >> 4;
  const int b = bh >> 4, h = bh & 15;

  short8 qfA[4], qfB[4];
  {
    const int qrowA = qt * 128 + w * 32 + l15;
    const unsigned short* qpA = qbuf + ((size_t)(b * 2048 + qrowA)) * 2048 + h * 128 + g * 8;
    const unsigned short* qpB = qpA + 16 * 2048;
#pragma unroll
    for (int kk = 0; kk < 4; ++kk) {
      qfA[kk] = *(const short8*)(qpA + kk * 32);
      qfB[kk] = *(const short8*)(qpB + kk * 32);
    }
  }
  f32x4 oA[8], oB[8];
#pragma unroll
  for (int d = 0; d < 8; ++d)
#pragma unroll
    for (int e = 0; e < 4; ++e) { oA[d][e] = 0.f; oB[d][e] = 0.f; }
  float mA = -1e30f, mB = -1e30f, lsA = 0.f, lsB = 0.f;

  const unsigned short* kbase = kfull + ((size_t)b * 4096) * 2048 + h * 128;
  const unsigned short* vbase = vfull + ((size_t)b * 4096) * 2048 + h * 128;

  const int vg4 = tid & 15;
  const int vdc = tid >> 4;
  const int vcol4 = (vg4 & 8) | ((vg4 & 3) << 1) | ((vg4 >> 2) & 1);  // column permute
  const int vu = vcol4 >> 1;
  const int vhalf = (vcol4 & 1) * 8;
  const int ksrow = l >> 4, ksu = l & 15;

  auto STAGEK = [&](int t, char* Kn) {
    const unsigned short* kb = kbase + (size_t)t * 64 * 2048;
#pragma unroll
    for (int ci = 0; ci < 4; ++ci) {
      const int c = w * 4 + ci;
      const int row = c * 4 + ksrow;
      GLD16(kb + (size_t)row * 2048 + ((ksu ^ (row & 7)) * 8), Kn + c * 1024);
    }
  };
  auto VLOAD = [&](int t, short8* r) {
    const unsigned short* vp = vbase + ((size_t)t * 64 + vg4 * 4) * 2048 + vdc * 8;
    r[0] = *(const short8*)(vp);
    r[1] = *(const short8*)(vp + 2048);
    r[2] = *(const short8*)(vp + 4096);
    r[3] = *(const short8*)(vp + 6144);
  };
  auto VWRITE = [&](char* Vn, short8* r) {
#pragma unroll
    for (int d = 0; d < 8; ++d) {
      const int row = vdc * 8 + d;
      const int mm = (d ^ vdc) & 7;               // (row ^ row>>3) & 7
      short4_ pk; pk[0] = r[0][d]; pk[1] = r[1][d]; pk[2] = r[2][d]; pk[3] = r[3][d];
      *(short4_*)(Vn + row * 128 + ((vu ^ mm) * 16) + vhalf) = pk;
    }
  };

  {
    short8 vr[4];
    STAGEK(0, smem);
    VLOAD(0, vr);
    VWRITE(smem + 16384, vr);
    __syncthreads();
  }

  for (int t = 0; t < 64; ++t) {
    char* Kc = smem + (t & 1) * 32768;
    char* Vc = Kc + 16384;
    char* Kn = smem + ((t + 1) & 1) * 32768;
    char* Vn = Kn + 16384;
    const bool pre = (t + 1) < 64;
    short8 vr[4];
    if (pre) {
      STAGEK(t + 1, Kn);   // async DMA into other buffer
      VLOAD(t + 1, vr);    // reg-staged; written to LDS after softmax (T14)
    }
    // --- QK^T (swapped): scX[kc] rows=keys, col=q ---
    f32x4 scA[4], scB[4];
    __builtin_amdgcn_s_setprio(1);
#pragma unroll
    for (int kc = 0; kc < 4; ++kc) {
      f32x4 a0, a1;
#pragma unroll
      for (int e = 0; e < 4; ++e) { a0[e] = 0.f; a1[e] = 0.f; }
      const int rowk = kc * 16 + l15;
      const int mk = rowk & 7;
#pragma unroll
      for (int kk = 0; kk < 4; ++kk) {
        short8 kf = *(const short8*)(Kc + rowk * 256 + (((kk * 4 + g) ^ mk) * 16));
        a0 = __builtin_amdgcn_mfma_f32_16x16x32_bf16(kf, qfA[kk], a0, 0, 0, 0);
        a1 = __builtin_amdgcn_mfma_f32_16x16x32_bf16(kf, qfB[kk], a1, 0, 0, 0);
      }
      scA[kc] = a0; scB[kc] = a1;
    }
    __builtin_amdgcn_s_setprio(0);

    // --- online softmax (max3 + cvt_pk packing) ---
    short8 pfA[2], pfB[2];
    {
      float tm = max3f(scA[0][0], scA[0][1], scA[0][2]);
      tm = max3f(tm, scA[0][3], scA[1][0]);
      tm = max3f(tm, scA[1][1], scA[1][2]);
      tm = max3f(tm, scA[1][3], scA[2][0]);
      tm = max3f(tm, scA[2][1], scA[2][2]);
      tm = max3f(tm, scA[2][3], scA[3][0]);
      tm = max3f(tm, scA[3][1], scA[3][2]);
      tm = fmaxf(tm, scA[3][3]);
      tm = fmaxf(tm, __shfl_xor(tm, 16, 64));
      tm = fmaxf(tm, __shfl_xor(tm, 32, 64));
      if (!__all(tm <= mA + 16.f)) {
        const float mn = fmaxf(mA, tm);
        const float f = exp2f(C2 * (mA - mn));
        mA = mn; lsA *= f;
#pragma unroll
        for (int d = 0; d < 8; ++d)
#pragma unroll
          for (int e = 0; e < 4; ++e) oA[d][e] *= f;
      }
      const float mc = C2 * mA;
      float p[4][4];
      float ps0 = 0.f, ps1 = 0.f;
#pragma unroll
      for (int kc = 0; kc < 4; ++kc) {
#pragma unroll
        for (int i = 0; i < 4; ++i) {
          p[kc][i] = exp2f(fmaf(C2, scA[kc][i], -mc));
          if (i & 1) ps1 += p[kc][i]; else ps0 += p[kc][i];
        }
      }
      float ps = ps0 + ps1;
      ps += __shfl_xor(ps, 16, 64);
      ps += __shfl_xor(ps, 32, 64);
      lsA += ps;
      u32x4 q0 = { cvtpk(p[0][0], p[0][1]), cvtpk(p[0][2], p[0][3]),
                   cvtpk(p[1][0], p[1][1]), cvtpk(p[1][2], p[1][3]) };
      u32x4 q1 = { cvtpk(p[2][0], p[2][1]), cvtpk(p[2][2], p[2][3]),
                   cvtpk(p[3][0], p[3][1]), cvtpk(p[3][2], p[3][3]) };
      pfA[0] = __builtin_bit_cast(short8, q0);
      pfA[1] = __builtin_bit_cast(short8, q1);
    }
    {
      float tm = max3f(scB[0][0], scB[0][1], scB[0][2]);
      tm = max3f(tm, scB[0][3], scB[1][0]);
      tm = max3f(tm, scB[1][1], scB[1][2]);
      tm = max3f(tm, scB[1][3], scB[2][0]);
      tm = max3f(tm, scB[2][1], scB[2][2]);
      tm = max3f(tm, scB[2][3], scB[3][0]);
      tm = max3f(tm, scB[3][1], scB[3][2]);
      tm = fmaxf(tm, scB[3][3]);
      tm = fmaxf(tm, __shfl_xor(tm, 16, 64));
      tm = fmaxf(tm, __shfl_xor(tm, 32, 64));
      if (!__all(tm <= mB + 16.f)) {
        const float mn = fmaxf(mB, tm);
        const float f = exp2f(C2 * (mB - mn));
        mB = mn; lsB *= f;
#pragma unroll
        for (int d = 0; d < 8; ++d)
#pragma unroll
          for (int e = 0; e < 4; ++e) oB[d][e] *= f;
      }
      const float mc = C2 * mB;
      float p[4][4];
      float ps0 = 0.f, ps1 = 0.f;
#pragma unroll
      for (int kc = 0; kc < 4; ++kc) {
#pragma unroll
        for (int i = 0; i < 4; ++i) {
          p[kc][i] = exp2f(fmaf(C2, scB[kc][i], -mc));
          if (i & 1) ps1 += p[kc][i]; else ps0 += p[kc][i];
        }
      }
      float ps = ps0 + ps1;
      ps += __shfl_xor(ps, 16, 64);
      ps += __shfl_xor(ps, 32, 64);
      lsB += ps;
      u32x4 q0 = { cvtpk(p[0][0], p[0][1]), cvtpk(p[0][2], p[0][3]),
                   cvtpk(p[1][0], p[1][1]), cvtpk(p[1][2], p[1][3]) };
      u32x4 q1 = { cvtpk(p[2][0], p[2][1]), cvtpk(p[2][2], p[2][3]),
                   cvtpk(p[3][0], p[3][1]), cvtpk(p[3][2], p[3][3]) };
      pfB[0] = __builtin_bit_cast(short8, q0);
      pfB[1] = __builtin_bit_cast(short8, q1);
    }

    if (pre) VWRITE(Vn, vr);   // write-late: HBM latency covered by QK^T + softmax

    // --- PV: O^T += V^T * P^T ---
    __builtin_amdgcn_s_setprio(1);
#pragma unroll
    for (int c = 0; c < 2; ++c) {
#pragma unroll
      for (int d = 0; d < 8; ++d) {
        const int rowv = d * 16 + l15;
        const int mv = (rowv ^ (rowv >> 3)) & 7;
        short8 vf = *(const short8*)(Vc + rowv * 128 + ((((c * 4 + g) ^ mv)) * 16));
        oA[d] = __builtin_amdgcn_mfma_f32_16x16x32_bf16(vf, pfA[c], oA[d], 0, 0, 0);
        oB[d] = __builtin_amdgcn_mfma_f32_16x16x32_bf16(vf, pfB[c], oB[d], 0, 0, 0);
      }
    }
    __builtin_amdgcn_s_setprio(0);
    __syncthreads();
  }

  // --- epilogue: normalize, bf16 transpose via LDS, coalesced store ---
  __syncthreads();
  const float invA = 1.0f / lsA, invB = 1.0f / lsB;
  char* ep = smem;   // [128 q][136 bf16]
#pragma unroll
  for (int d = 0; d < 8; ++d) {
    short4_ pa, pb;
#pragma unroll
    for (int e = 0; e < 4; ++e) {
      pa[e] = (short)f2bf(oA[d][e] * invA);
      pb[e] = (short)f2bf(oB[d][e] * invB);
    }
    const int colb = (d * 16 + g * 4) * 2;
    *(short4_*)(ep + (w * 32 + l15) * 272 + colb) = pa;
    *(short4_*)(ep + (w * 32 + 16 + l15) * 272 + colb) = pb;
  }
  __syncthreads();
#pragma unroll
  for (int i = 0; i < 8; ++i) {
    const int task = tid + i * 256;
    const int row = task >> 4, un = task & 15;
    short8 ov = *(const short8*)(ep + row * 272 + un * 16);
    const int qg = qt * 128 + row;
    *(short8*)(attnout + ((size_t)(b * 2048 + qg)) * 2048 + h * 128 + un * 8) = ov;
  }
}

// ---------------- host launcher ----------------
extern "C" void kernel_launch(void* const* d_in, const int* in_sizes, int n_in,
                              void* d_out, int out_size, void* d_ws, size_t ws_size,
                              hipStream_t stream)
{
  const float* x  = (const float*)d_in[0];
  const float* ck = (const float*)d_in[1];
  const float* cv = (const float*)d_in[2];
  const float* wq = (const float*)d_in[3];
  const float* bq = (const float*)d_in[4];
  const float* wk = (const float*)d_in[5];
  const float* bk = (const float*)d_in[6];
  const float* wv = (const float*)d_in[7];
  const float* bv = (const float*)d_in[8];
  const float* wo = (const float*)d_in[9];
  const float* bo = (const float*)d_in[10];
  float* out = (float*)d_out;

  char* ws = (char*)d_ws;
  unsigned short* xbf   = (unsigned short*)(ws);                 // 16 MB
  unsigned short* wqkvT = (unsigned short*)(ws + 16777216ull);   // 24 MB
  unsigned short* woT   = (unsigned short*)(ws + 41943040ull);   // 8 MB
  unsigned short* qbuf  = (unsigned short*)(ws + 50331648ull);   // 16 MB
  unsigned short* kfull = (unsigned short*)(ws + 67108864ull);   // 32 MB
  unsigned short* vfull = (unsigned short*)(ws + 100663296ull);  // 32 MB
  unsigned short* aout  = (unsigned short*)(ws + 134217728ull);  // 16 MB

  (void)hipFuncSetAttribute((const void*)k_gemm8,
                            hipFuncAttributeMaxDynamicSharedMemorySize, 131072);

  k_transpose_w<<<dim3(32, 32, 4), 256, 0, stream>>>(wq, wk, wv, wo, wqkvT, woT);
  k_convert<<<dim3(4096, 3), 256, 0, stream>>>(x, ck, cv, xbf, kfull, vfull);
  k_gemm8<<<dim3(384), 512, 131072, stream>>>(xbf, wqkvT, qbuf, kfull, vfull, bq, bk, bv);
  k_flash<<<dim3(512), 256, 0, stream>>>(qbuf, kfull, vfull, aout);
  k_gemmo<<<dim3(16, 32), 256, 0, stream>>>(aout, woT, out, bo, 2048);
}